// Round 18
// baseline (179.633 us; speedup 1.0000x reference)
//
#include <hip/hip_runtime.h>
#include <cstdint>

typedef __attribute__((ext_vector_type(8))) __bf16 bf16x8;
typedef __attribute__((ext_vector_type(8))) unsigned short u16x8;
typedef __attribute__((ext_vector_type(4))) unsigned short u16x4;
typedef __attribute__((ext_vector_type(4))) float f32x4;
typedef __attribute__((ext_vector_type(2))) unsigned int u32x2;
typedef __attribute__((ext_vector_type(4))) unsigned int u32x4;

__device__ inline unsigned short f2bf(float f) {
  // native cast -> compiler emits v_cvt_pk_bf16_f32 (RNE) and pairs adjacent converts
  return __builtin_bit_cast(unsigned short, (__bf16)f);
}

__device__ inline void llds16(const void* g, void* l) {
  // async global->LDS, 16B per lane; LDS dest must be wave-uniform base (+lane*16 implicit)
  __builtin_amdgcn_global_load_lds((const uint32_t*)g, (uint32_t*)l, 16, 0, 0);
}

__device__ inline bf16x8 ldfrag(const unsigned short* p) {
  u16x8 v = *(const u16x8*)p;
  return __builtin_bit_cast(bf16x8, v);
}

__device__ inline f32x4 mfma16(bf16x8 a, bf16x8 b, f32x4 c) {
  return __builtin_amdgcn_mfma_f32_16x16x32_bf16(a, b, c, 0, 0, 0);
}

// ---------------- fused prep: LayerNorm (blocks 0..8191) + weight transpose-cast ------------
// ln: one block per row (1024 cols), 256 threads x 4 elements -> xn (LN) + xb (raw) bf16.
// wcast: blocks 8192..9215 = 4 matrices x 256 tiles of 64x64: W(K,N) fp32 -> WT(N,K) bf16.
// wcast vectorized: float4 loads of W, packed u16x4 stores of WT.
__global__ __launch_bounds__(256) void prep_kernel(
    const float* __restrict__ x, const float* __restrict__ g, const float* __restrict__ be,
    unsigned short* __restrict__ xn, unsigned short* __restrict__ xb,
    const float* __restrict__ wq, const float* __restrict__ wk,
    const float* __restrict__ wv, const float* __restrict__ wo,
    unsigned short* __restrict__ wT, unsigned short* __restrict__ woT)
{
  __shared__ float t[64][66];            // wcast tile (ln uses first 8 floats only)
  const int tid = threadIdx.x;
  if (blockIdx.x < 8192) {
    const int row = blockIdx.x;
    const size_t base = (size_t)row * 1024 + tid * 4;
    float4 v = *(const float4*)&x[base];
    float s  = v.x + v.y + v.z + v.w;
    float sq = v.x*v.x + v.y*v.y + v.z*v.z + v.w*v.w;
#pragma unroll
    for (int o = 1; o < 64; o <<= 1) { s += __shfl_xor(s, o); sq += __shfl_xor(sq, o); }
    float* ls = &t[0][0];
    if ((tid & 63) == 0) { ls[tid >> 6] = s; ls[4 + (tid >> 6)] = sq; }
    __syncthreads();
    s  = ls[0] + ls[1] + ls[2] + ls[3];
    sq = ls[4] + ls[5] + ls[6] + ls[7];
    const float mu   = s * (1.f / 1024.f);
    const float var  = sq * (1.f / 1024.f) - mu * mu;
    const float rstd = rsqrtf(var + 1e-5f);
    float4 gv = *(const float4*)&g[tid * 4];
    float4 bv = *(const float4*)&be[tid * 4];
    u16x4 a, bb;
    a[0] = f2bf((v.x - mu) * rstd * gv.x + bv.x);
    a[1] = f2bf((v.y - mu) * rstd * gv.y + bv.y);
    a[2] = f2bf((v.z - mu) * rstd * gv.z + bv.z);
    a[3] = f2bf((v.w - mu) * rstd * gv.w + bv.w);
    bb[0] = f2bf(v.x); bb[1] = f2bf(v.y); bb[2] = f2bf(v.z); bb[3] = f2bf(v.w);
    *(u16x4*)&xn[base] = a;
    *(u16x4*)&xb[base] = bb;
  } else {
    const int zz = blockIdx.x - 8192;    // 0..1023
    const int z = zz >> 8;               // matrix 0..3
    const int rem = zz & 255;
    const int n0 = (rem & 15) * 64, k0 = (rem >> 4) * 64;
    const float* W = (z == 0) ? wq : (z == 1) ? wk : (z == 2) ? wv : wo;
    unsigned short* O = (z < 3) ? (wT + (size_t)z * 1048576) : woT;
    // load: 64x64 fp32 tile, float4 per lane (16B), 4 iters
    for (int idx = tid; idx < 1024; idx += 256) {
      int r = idx >> 4, c4 = (idx & 15) * 4;
      float4 w = *(const float4*)&W[(size_t)(k0 + r) * 1024 + n0 + c4];
      t[r][c4] = w.x; t[r][c4 + 1] = w.y; t[r][c4 + 2] = w.z; t[r][c4 + 3] = w.w;
    }
    __syncthreads();
    // store: transposed rows are contiguous in k -> packed u16x4 (8B), 4 iters
    for (int idx = tid; idx < 1024; idx += 256) {
      int r = idx >> 4, c4 = (idx & 15) * 4;   // r = n offset, c4 = k offset (x4)
      u16x4 pk;
#pragma unroll
      for (int j = 0; j < 4; j++) pk[j] = f2bf(t[c4 + j][r]);
      *(u16x4*)&O[(size_t)(n0 + r) * 1024 + k0 + c4] = pk;
    }
  }
}

// ---------------- 128x128x(BK=64) bf16 GEMM, single-buffer (m97 loop) + T2 + chunking -------
// R18: dbuf removed. 32KB LDS -> ~5 blocks/CU (20 waves/CU, was 8 with 64KB dbuf): cross-
// block TLP (m114) covers each block's stage->drain->compute serialization; reference m97/
// m157 measured 874-948 TF with exactly this single-buffered loop. Keeps T2 XOR swizzle,
// XCD-chunked bm-fast grid (R17: FETCH 117->49MB), setprio, epilogues.
// MODE 0: q (scaled 0.125*log2(e)) | k in (bh,t,64); V written directly transposed (bh,64,t).
// MODE 1: C = A @ BT^T + bias -> fp32 row-major.
template<int MODE>
__global__ __launch_bounds__(256) void gemm_kernel(
    const unsigned short* __restrict__ A0, const unsigned short* __restrict__ A1,
    const unsigned short* __restrict__ BT,
    const float* __restrict__ b0, const float* __restrict__ b1, const float* __restrict__ b2,
    void* __restrict__ Cv, int M, int N, int K)
{
  __shared__ unsigned short S[16384];   // A 8192 us | B 8192 us = 32 KB (single buffer)
  const int tid = threadIdx.x;
  const int wave = tid >> 6, lane = tid & 63;
  const int l15 = lane & 15, l4 = lane >> 4;
  const int swz = (l15 & 7) << 3;       // read-side XOR, ushort units (16B granules)
  const int NBN = N >> 7;
  const int nwg = gridDim.x, cpx = nwg >> 3;
  const int orig = blockIdx.x;
  const int id = (orig & 7) * cpx + (orig >> 3);   // XCD-chunked (nwg%8==0)
  // bm-fast within 8-bm groups: one 256KB B panel shared by 8 blocks; B streams L2 once
  const int grp = id / (NBN * 8);
  const int rem = id % (NBN * 8);
  const int bn = rem >> 3;
  const int bm = grp * 8 + (rem & 7);
  const int m0 = bm * 128, n0 = bn * 128;
  const unsigned short* Ap = (MODE == 0 && bn >= 8) ? A1 : A0;
  const int wr = (wave >> 1) * 64, wc = (wave & 1) * 64;

  f32x4 acc[4][4];
#pragma unroll
  for (int m = 0; m < 4; m++)
#pragma unroll
    for (int n = 0; n < 4; n++) acc[m][n] = {0.f, 0.f, 0.f, 0.f};

  auto STAGE = [&](int kt) {
#pragma unroll
    for (int r = 0; r < 4; r++) {
      int D = r * 4096 + tid * 16;      // phys byte offset in tile
      int row = D >> 7;
      int colus = ((D & 127) >> 1) ^ ((row & 7) << 3);   // logical col for this phys slot
      llds16(&Ap[(size_t)(m0 + row) * K + kt + colus], &S[r * 2048 + wave * 512]);
      llds16(&BT[(size_t)(n0 + row) * K + kt + colus], &S[8192 + r * 2048 + wave * 512]);
    }
  };

  const int KSTEPS = K >> 6;
  for (int ki = 0; ki < KSTEPS; ki++) {
    __syncthreads();                     // all waves done reading previous tile
    STAGE(ki << 6);
    __syncthreads();                     // data ready (compiler drains vmcnt before barrier)
#pragma unroll
    for (int ks = 0; ks < 2; ks++) {
      bf16x8 af[4], bfr[4];
#pragma unroll
      for (int m = 0; m < 4; m++)
        af[m]  = ldfrag(&S[(wr + m * 16 + l15) * 64 + ((ks * 32 + l4 * 8) ^ swz)]);
#pragma unroll
      for (int n = 0; n < 4; n++)
        bfr[n] = ldfrag(&S[8192 + (wc + n * 16 + l15) * 64 + ((ks * 32 + l4 * 8) ^ swz)]);
      __builtin_amdgcn_s_setprio(1);
#pragma unroll
      for (int m = 0; m < 4; m++)
#pragma unroll
        for (int n = 0; n < 4; n++)
          acc[m][n] = mfma16(af[m], bfr[n], acc[m][n]);
      __builtin_amdgcn_s_setprio(0);
    }
  }

#pragma unroll
  for (int nf = 0; nf < 4; nf++) {
    int c = n0 + wc + nf * 16 + l15;
    if (MODE == 0) {
      int sec = c >> 10;
      float bias = (sec == 0 ? b0 : (sec == 1 ? b1 : b2))[c & 1023];
      float sc = (sec == 0) ? 0.18033688011112042f : 1.0f;  // 0.125*log2(e) on q
      int h = (c >> 6) & 15, d = c & 63;
#pragma unroll
      for (int mf = 0; mf < 4; mf++) {
        int rbase = m0 + wr + mf * 16 + l4 * 4;
        int b = rbase >> 11, t = rbase & 2047;   // 4 regs = t..t+3 (t%4==0, no b crossing)
        if (sec == 2) {
          // V: write directly in (bh, 64, t) transposed layout, packed 4x bf16 (8B)
          u16x4 pk;
#pragma unroll
          for (int reg = 0; reg < 4; reg++) pk[reg] = f2bf(acc[mf][nf][reg] + bias);
          *(u16x4*)&((unsigned short*)Cv)[(size_t)2 * 8388608 +
                                          ((size_t)((b * 16 + h) * 64 + d)) * 2048 + t] = pk;
        } else {
#pragma unroll
          for (int reg = 0; reg < 4; reg++) {
            float v = acc[mf][nf][reg] + bias;
            ((unsigned short*)Cv)[(size_t)sec * 8388608 +
                                  ((size_t)(b * 16 + h) * 2048 + t + reg) * 64 + d] =
                f2bf(v * sc);
          }
        }
      }
    } else {
      float bias = b0[c];
#pragma unroll
      for (int mf = 0; mf < 4; mf++) {
#pragma unroll
        for (int reg = 0; reg < 4; reg++) {
          int rrow = m0 + wr + mf * 16 + l4 * 4 + reg;
          ((float*)Cv)[(size_t)rrow * N + c] = acc[mf][nf][reg] + bias;
        }
      }
    }
  }
}

// ---------------- attention: 256 q-rows/block, 8 waves x 32 rows (R9 structure, proven) ----
// dbuf + issue-early STAGE + counted vmcnt(4), T2 swizzle, in-register P relayout via
// permlane, ones-MFMA rowsum, exp2 with Q pre-scaled by 0.125*log2(e), XCD swizzle.
__global__ __launch_bounds__(512, 4) void attn_kernel(
    const unsigned short* __restrict__ Q,   // (bh, s, 64), pre-scaled
    const unsigned short* __restrict__ Kg,  // (bh, t, 64)
    const unsigned short* __restrict__ VTg, // (bh, 64, t)
    unsigned short* __restrict__ Oa)        // (b, s, 1024) bf16
{
  __shared__ unsigned short S[32768];    // [buf][K 8192 us | V 8192 us] x2 = 64 KB
  const int tid = threadIdx.x;
  const int wave = tid >> 6, lane = tid & 63;
  const int l15 = lane & 15, l4 = lane >> 4;
  const int swz = (l15 & 7) << 3;        // read-side XOR, ushort units (16B granules)
  // bijective XCD swizzle (nwg=512): XCD gets 64 contiguous wg = 8 bh x 8 qb
  const int orig = blockIdx.x;
  const int wg = ((orig & 7) << 6) + (orig >> 3);
  const int qb = wg & 7, bh = wg >> 3;
  const size_t bhbase = (size_t)bh * 131072;
  const int q0 = qb * 256 + wave * 32;

  const u16x8 onesu = {0x3F80, 0x3F80, 0x3F80, 0x3F80, 0x3F80, 0x3F80, 0x3F80, 0x3F80};
  const bf16x8 ones = __builtin_bit_cast(bf16x8, onesu);

  bf16x8 qf[2][2];
#pragma unroll
  for (int m = 0; m < 2; m++)
#pragma unroll
    for (int ks = 0; ks < 2; ks++)
      qf[m][ks] = ldfrag(&Q[bhbase + (size_t)(q0 + m * 16 + l15) * 64 + ks * 32 + l4 * 8]);

  f32x4 accO[2][4];
#pragma unroll
  for (int m = 0; m < 2; m++)
#pragma unroll
    for (int n = 0; n < 4; n++) accO[m][n] = {0.f, 0.f, 0.f, 0.f};
  f32x4 accR[2] = {{0.f, 0.f, 0.f, 0.f}, {0.f, 0.f, 0.f, 0.f}};

  // stage tile jj into buffer b: 4 llds16/thread (2 K rounds + 2 V rounds), 512 threads
  auto STAGE = [&](int b, int jj) {
#pragma unroll
    for (int r = 0; r < 2; r++) {
      int D = r * 8192 + tid * 16;     // byte offset within 16KB tile
      int rowK = D >> 7;
      int colKus = ((D & 127) >> 1) ^ ((rowK & 7) << 3);
      llds16(&Kg[bhbase + (size_t)(jj * 128 + rowK) * 64 + colKus],
             &S[b * 16384 + r * 4096 + wave * 512]);
      int rowV = D >> 8;
      int colVus = ((D & 255) >> 1) ^ ((rowV & 7) << 3);
      llds16(&VTg[bhbase + (size_t)rowV * 2048 + jj * 128 + colVus],
             &S[b * 16384 + 8192 + r * 4096 + wave * 512]);
    }
  };

  int cur = 0;
  STAGE(0, 0);
  for (int j = 0; j < 16; j++) {
    if (j < 15) {
      STAGE(cur ^ 1, j + 1);
      asm volatile("s_waitcnt vmcnt(4)" ::: "memory");   // cur's 4 loads landed; j+1's in flight
    } else {
      asm volatile("s_waitcnt vmcnt(0)" ::: "memory");
    }
    __builtin_amdgcn_s_barrier();                        // all waves: cur data ready
    __builtin_amdgcn_sched_barrier(0);

    const unsigned short* Kb = &S[cur * 16384];
    const unsigned short* Vb = &S[cur * 16384 + 8192];

#pragma unroll
    for (int kt = 0; kt < 4; kt++) {
      // QK^T for the two 16-t fragments of this 32-t block
      bf16x8 kf00 = ldfrag(&Kb[((2 * kt) * 16 + l15) * 64 + ((0 * 32 + l4 * 8) ^ swz)]);
      bf16x8 kf01 = ldfrag(&Kb[((2 * kt) * 16 + l15) * 64 + ((1 * 32 + l4 * 8) ^ swz)]);
      bf16x8 kf10 = ldfrag(&Kb[((2 * kt + 1) * 16 + l15) * 64 + ((0 * 32 + l4 * 8) ^ swz)]);
      bf16x8 kf11 = ldfrag(&Kb[((2 * kt + 1) * 16 + l15) * 64 + ((1 * 32 + l4 * 8) ^ swz)]);
      f32x4 sa = {0.f, 0.f, 0.f, 0.f}, sb = sa, sc = sa, sd = sa;
      __builtin_amdgcn_s_setprio(1);
      sa = mfma16(kf00, qf[0][0], sa); sb = mfma16(kf00, qf[1][0], sb);
      sc = mfma16(kf10, qf[0][0], sc); sd = mfma16(kf10, qf[1][0], sd);
      sa = mfma16(kf01, qf[0][1], sa); sb = mfma16(kf01, qf[1][1], sb);
      sc = mfma16(kf11, qf[0][1], sc); sd = mfma16(kf11, qf[1][1], sd);
      __builtin_amdgcn_s_setprio(0);

      // V fragments (independent of QK chain -> overlaps MFMA latency)
      bf16x8 vf[4];
#pragma unroll
      for (int n = 0; n < 4; n++)
        vf[n] = ldfrag(&Vb[(n * 16 + l15) * 128 + ((kt * 32 + l4 * 8) ^ swz)]);

      // exp2 + pack + 4x4 u32 transpose over l4 groups:
      //   dest lane(g1,g0) word(w1,w0) <- lane(g0,w1) word(g1,w0)
      bf16x8 pf[2];
#pragma unroll
      for (int m = 0; m < 2; m++) {
        const f32x4 se = (m == 0) ? sa : sb;   // tf = 2kt
        const f32x4 so = (m == 0) ? sc : sd;   // tf = 2kt+1
        uint32_t V0, V1, V2, V3;
        {
          u16x4 pk;
#pragma unroll
          for (int r = 0; r < 4; r++) pk[r] = f2bf(__builtin_amdgcn_exp2f(se[r]));
          u32x2 w = __builtin_bit_cast(u32x2, pk);
          V0 = w[0]; V1 = w[1];
        }
        {
          u16x4 pk;
#pragma unroll
          for (int r = 0; r < 4; r++) pk[r] = f2bf(__builtin_amdgcn_exp2f(so[r]));
          u32x2 w = __builtin_bit_cast(u32x2, pk);
          V2 = w[0]; V3 = w[1];
        }
        asm("s_nop 1\n\t"
            "v_permlane32_swap_b32 %0, %2\n\t"
            "v_permlane32_swap_b32 %1, %3\n\t"
            "v_permlane16_swap_b32 %0, %2\n\t"
            "v_permlane16_swap_b32 %1, %3"
            : "+v"(V0), "+v"(V1), "+v"(V2), "+v"(V3));
        u32x4 fw = {V0, V1, V2, V3};
        pf[m] = __builtin_bit_cast(bf16x8, fw);
      }

      __builtin_amdgcn_s_setprio(1);
#pragma unroll
      for (int m = 0; m < 2; m++) {
        accR[m] = mfma16(pf[m], ones, accR[m]);   // rowsum on the matrix pipe
#pragma unroll
        for (int n = 0; n < 4; n++)
          accO[m][n] = mfma16(pf[m], vf[n], accO[m][n]);
      }
      __builtin_amdgcn_s_setprio(0);
    }

    __builtin_amdgcn_s_barrier();        // all waves done reading cur -> safe to overwrite
    cur ^= 1;
  }

  const int b = bh >> 4, h = bh & 15;
#pragma unroll
  for (int m = 0; m < 2; m++)
#pragma unroll
    for (int reg = 0; reg < 4; reg++) {
      float inv = 1.0f / accR[m][reg];   // rowsum for srow (C layout: row = l4*4+reg)
      int srow = q0 + m * 16 + l4 * 4 + reg;
#pragma unroll
      for (int n = 0; n < 4; n++) {
        float v = accO[m][n][reg] * inv;
        Oa[((size_t)(b * 2048) + srow) * 1024 + h * 64 + n * 16 + l15] = f2bf(v);
      }
    }
}

extern "C" void kernel_launch(void* const* d_in, const int* in_sizes, int n_in,
                              void* d_out, int out_size, void* d_ws, size_t ws_size,
                              hipStream_t stream) {
  (void)in_sizes; (void)n_in; (void)out_size; (void)ws_size;
  const float* x   = (const float*)d_in[0];
  const float* lng = (const float*)d_in[1];
  const float* lnb = (const float*)d_in[2];
  const float* wq  = (const float*)d_in[3];
  const float* bq  = (const float*)d_in[4];
  const float* wk  = (const float*)d_in[5];
  const float* bk  = (const float*)d_in[6];
  const float* wv  = (const float*)d_in[7];
  const float* bv  = (const float*)d_in[8];
  const float* wo  = (const float*)d_in[9];
  const float* bo  = (const float*)d_in[10];

  unsigned short* ws = (unsigned short*)d_ws;
  const size_t NE = 8388608;                    // 8192*1024
  unsigned short* xn  = ws;                     // bf16 LN(x)
  unsigned short* xb  = ws + NE;                // bf16 raw x
  unsigned short* wT  = ws + 2 * NE;            // (3072,1024) W^T bf16
  unsigned short* woT = wT + 3145728;           // (1024,1024) wo^T bf16
  unsigned short* qkv = woT + 1048576;          // q|k (bh,t,64) | vT (bh,64,t) bf16
  unsigned short* oat = xb;                     // alias: xb dead after GEMM1

  prep_kernel<<<dim3(9216), 256, 0, stream>>>(x, lng, lnb, xn, xb, wq, wk, wv, wo, wT, woT);
  gemm_kernel<0><<<dim3(1536), 256, 0, stream>>>(xn, xb, wT, bq, bk, bv, qkv, 8192, 3072, 1024);
  attn_kernel<<<dim3(512), 512, 0, stream>>>(qkv, qkv + NE, qkv + 2 * NE, oat);
  gemm_kernel<1><<<dim3(512), 256, 0, stream>>>(oat, oat, woT, bo, bo, bo, d_out, 8192, 1024, 1024);
}

// Round 19
// 169.968 us; speedup vs baseline: 1.0569x; 1.0569x over previous
//
#include <hip/hip_runtime.h>
#include <cstdint>

typedef __attribute__((ext_vector_type(8))) __bf16 bf16x8;
typedef __attribute__((ext_vector_type(8))) unsigned short u16x8;
typedef __attribute__((ext_vector_type(4))) unsigned short u16x4;
typedef __attribute__((ext_vector_type(4))) float f32x4;
typedef __attribute__((ext_vector_type(2))) unsigned int u32x2;
typedef __attribute__((ext_vector_type(4))) unsigned int u32x4;

__device__ inline unsigned short f2bf(float f) {
  // native cast -> compiler emits v_cvt_pk_bf16_f32 (RNE) and pairs adjacent converts
  return __builtin_bit_cast(unsigned short, (__bf16)f);
}

__device__ inline void llds16(const void* g, void* l) {
  // async global->LDS, 16B per lane; LDS dest must be wave-uniform base (+lane*16 implicit)
  __builtin_amdgcn_global_load_lds((const uint32_t*)g, (uint32_t*)l, 16, 0, 0);
}

__device__ inline bf16x8 ldfrag(const unsigned short* p) {
  u16x8 v = *(const u16x8*)p;
  return __builtin_bit_cast(bf16x8, v);
}

__device__ inline f32x4 mfma16(bf16x8 a, bf16x8 b, f32x4 c) {
  return __builtin_amdgcn_mfma_f32_16x16x32_bf16(a, b, c, 0, 0, 0);
}

// ---------------- fused prep: LayerNorm (blocks 0..8191) + weight transpose-cast ------------
// ln: one block per row (1024 cols), 256 threads x 4 elements -> xn (LN) + xb (raw) bf16.
// wcast: blocks 8192..9215 = 4 matrices x 256 tiles of 64x64: W(K,N) fp32 -> WT(N,K) bf16.
// wcast vectorized: float4 loads of W, packed u16x4 stores of WT.
__global__ __launch_bounds__(256) void prep_kernel(
    const float* __restrict__ x, const float* __restrict__ g, const float* __restrict__ be,
    unsigned short* __restrict__ xn, unsigned short* __restrict__ xb,
    const float* __restrict__ wq, const float* __restrict__ wk,
    const float* __restrict__ wv, const float* __restrict__ wo,
    unsigned short* __restrict__ wT, unsigned short* __restrict__ woT)
{
  __shared__ float t[64][66];            // wcast tile (ln uses first 8 floats only)
  const int tid = threadIdx.x;
  if (blockIdx.x < 8192) {
    const int row = blockIdx.x;
    const size_t base = (size_t)row * 1024 + tid * 4;
    float4 v = *(const float4*)&x[base];
    float s  = v.x + v.y + v.z + v.w;
    float sq = v.x*v.x + v.y*v.y + v.z*v.z + v.w*v.w;
#pragma unroll
    for (int o = 1; o < 64; o <<= 1) { s += __shfl_xor(s, o); sq += __shfl_xor(sq, o); }
    float* ls = &t[0][0];
    if ((tid & 63) == 0) { ls[tid >> 6] = s; ls[4 + (tid >> 6)] = sq; }
    __syncthreads();
    s  = ls[0] + ls[1] + ls[2] + ls[3];
    sq = ls[4] + ls[5] + ls[6] + ls[7];
    const float mu   = s * (1.f / 1024.f);
    const float var  = sq * (1.f / 1024.f) - mu * mu;
    const float rstd = rsqrtf(var + 1e-5f);
    float4 gv = *(const float4*)&g[tid * 4];
    float4 bv = *(const float4*)&be[tid * 4];
    u16x4 a, bb;
    a[0] = f2bf((v.x - mu) * rstd * gv.x + bv.x);
    a[1] = f2bf((v.y - mu) * rstd * gv.y + bv.y);
    a[2] = f2bf((v.z - mu) * rstd * gv.z + bv.z);
    a[3] = f2bf((v.w - mu) * rstd * gv.w + bv.w);
    bb[0] = f2bf(v.x); bb[1] = f2bf(v.y); bb[2] = f2bf(v.z); bb[3] = f2bf(v.w);
    *(u16x4*)&xn[base] = a;
    *(u16x4*)&xb[base] = bb;
  } else {
    const int zz = blockIdx.x - 8192;    // 0..1023
    const int z = zz >> 8;               // matrix 0..3
    const int rem = zz & 255;
    const int n0 = (rem & 15) * 64, k0 = (rem >> 4) * 64;
    const float* W = (z == 0) ? wq : (z == 1) ? wk : (z == 2) ? wv : wo;
    unsigned short* O = (z < 3) ? (wT + (size_t)z * 1048576) : woT;
    // load: 64x64 fp32 tile, float4 per lane (16B), 4 iters
    for (int idx = tid; idx < 1024; idx += 256) {
      int r = idx >> 4, c4 = (idx & 15) * 4;
      float4 w = *(const float4*)&W[(size_t)(k0 + r) * 1024 + n0 + c4];
      t[r][c4] = w.x; t[r][c4 + 1] = w.y; t[r][c4 + 2] = w.z; t[r][c4 + 3] = w.w;
    }
    __syncthreads();
    // store: transposed rows are contiguous in k -> packed u16x4 (8B), 4 iters
    for (int idx = tid; idx < 1024; idx += 256) {
      int r = idx >> 4, c4 = (idx & 15) * 4;   // r = n offset, c4 = k offset (x4)
      u16x4 pk;
#pragma unroll
      for (int j = 0; j < 4; j++) pk[j] = f2bf(t[c4 + j][r]);
      *(u16x4*)&O[(size_t)(n0 + r) * 1024 + k0 + c4] = pk;
    }
  }
}

// ---------------- 128x128x(BK=64) bf16 GEMM + T2 swizzle + XCD chunking + dbuf pipeline ----
// (R17 configuration — session best.) Dbuf + issue-early STAGE + counted vmcnt(8); bm-fast
// ordering within each XCD chunk (one 256KB B panel shared by 8 consecutive blocks -> B
// streams each XCD's L2 exactly once; FETCH 117->49MB measured).
// MODE 0: q (scaled 0.125*log2(e)) | k in (bh,t,64); V written directly transposed (bh,64,t).
// MODE 1: C = A @ BT^T + bias -> fp32 row-major.
template<int MODE>
__global__ __launch_bounds__(256) void gemm_kernel(
    const unsigned short* __restrict__ A0, const unsigned short* __restrict__ A1,
    const unsigned short* __restrict__ BT,
    const float* __restrict__ b0, const float* __restrict__ b1, const float* __restrict__ b2,
    void* __restrict__ Cv, int M, int N, int K)
{
  __shared__ unsigned short S[32768];   // [buf][A 8192 us | B 8192 us] x2 = 64 KB
  const int tid = threadIdx.x;
  const int wave = tid >> 6, lane = tid & 63;
  const int l15 = lane & 15, l4 = lane >> 4;
  const int swz = (l15 & 7) << 3;       // read-side XOR, ushort units (16B granules)
  const int NBN = N >> 7;
  const int nwg = gridDim.x, cpx = nwg >> 3;
  const int orig = blockIdx.x;
  const int id = (orig & 7) * cpx + (orig >> 3);   // XCD-chunked (nwg%8==0)
  // bm-fast within 8-bm groups: id -> (group of 8 bm) x (bn) x (bm within group)
  const int grp = id / (NBN * 8);
  const int rem = id % (NBN * 8);
  const int bn = rem >> 3;
  const int bm = grp * 8 + (rem & 7);
  const int m0 = bm * 128, n0 = bn * 128;
  const unsigned short* Ap = (MODE == 0 && bn >= 8) ? A1 : A0;
  const int wr = (wave >> 1) * 64, wc = (wave & 1) * 64;

  f32x4 acc[4][4];
#pragma unroll
  for (int m = 0; m < 4; m++)
#pragma unroll
    for (int n = 0; n < 4; n++) acc[m][n] = {0.f, 0.f, 0.f, 0.f};

  auto STAGE = [&](int b, int kt) {
#pragma unroll
    for (int r = 0; r < 4; r++) {
      int D = r * 4096 + tid * 16;      // phys byte offset in tile
      int row = D >> 7;
      int colus = ((D & 127) >> 1) ^ ((row & 7) << 3);   // logical col for this phys slot
      llds16(&Ap[(size_t)(m0 + row) * K + kt + colus], &S[b * 16384 + r * 2048 + wave * 512]);
      llds16(&BT[(size_t)(n0 + row) * K + kt + colus],
             &S[b * 16384 + 8192 + r * 2048 + wave * 512]);
    }
  };

  const int KSTEPS = K >> 6;
  int cur = 0;
  STAGE(0, 0);
  for (int ki = 0; ki < KSTEPS; ki++) {
    if (ki < KSTEPS - 1) {
      STAGE(cur ^ 1, (ki + 1) << 6);
      asm volatile("s_waitcnt vmcnt(8)" ::: "memory");   // cur's 8 landed; next 8 in flight
    } else {
      asm volatile("s_waitcnt vmcnt(0)" ::: "memory");
    }
    __builtin_amdgcn_s_barrier();                        // cur data ready for all waves
    __builtin_amdgcn_sched_barrier(0);
    const unsigned short* Asb = &S[cur * 16384];
    const unsigned short* Bsb = &S[cur * 16384 + 8192];
#pragma unroll
    for (int ks = 0; ks < 2; ks++) {
      bf16x8 af[4], bfr[4];
#pragma unroll
      for (int m = 0; m < 4; m++)
        af[m]  = ldfrag(&Asb[(wr + m * 16 + l15) * 64 + ((ks * 32 + l4 * 8) ^ swz)]);
#pragma unroll
      for (int n = 0; n < 4; n++)
        bfr[n] = ldfrag(&Bsb[(wc + n * 16 + l15) * 64 + ((ks * 32 + l4 * 8) ^ swz)]);
#pragma unroll
      for (int m = 0; m < 4; m++)
#pragma unroll
        for (int n = 0; n < 4; n++)
          acc[m][n] = mfma16(af[m], bfr[n], acc[m][n]);
    }
    __builtin_amdgcn_s_barrier();        // all waves done reading cur -> safe to overwrite
    cur ^= 1;
  }

#pragma unroll
  for (int nf = 0; nf < 4; nf++) {
    int c = n0 + wc + nf * 16 + l15;
    if (MODE == 0) {
      int sec = c >> 10;
      float bias = (sec == 0 ? b0 : (sec == 1 ? b1 : b2))[c & 1023];
      float sc = (sec == 0) ? 0.18033688011112042f : 1.0f;  // 0.125*log2(e) on q
      int h = (c >> 6) & 15, d = c & 63;
#pragma unroll
      for (int mf = 0; mf < 4; mf++) {
        int rbase = m0 + wr + mf * 16 + l4 * 4;
        int b = rbase >> 11, t = rbase & 2047;   // 4 regs = t..t+3 (t%4==0, no b crossing)
        if (sec == 2) {
          // V: write directly in (bh, 64, t) transposed layout, packed 4x bf16 (8B)
          u16x4 pk;
#pragma unroll
          for (int reg = 0; reg < 4; reg++) pk[reg] = f2bf(acc[mf][nf][reg] + bias);
          *(u16x4*)&((unsigned short*)Cv)[(size_t)2 * 8388608 +
                                          ((size_t)((b * 16 + h) * 64 + d)) * 2048 + t] = pk;
        } else {
#pragma unroll
          for (int reg = 0; reg < 4; reg++) {
            float v = acc[mf][nf][reg] + bias;
            ((unsigned short*)Cv)[(size_t)sec * 8388608 +
                                  ((size_t)(b * 16 + h) * 2048 + t + reg) * 64 + d] =
                f2bf(v * sc);
          }
        }
      }
    } else {
      float bias = b0[c];
#pragma unroll
      for (int mf = 0; mf < 4; mf++) {
#pragma unroll
        for (int reg = 0; reg < 4; reg++) {
          int rrow = m0 + wr + mf * 16 + l4 * 4 + reg;
          ((float*)Cv)[(size_t)rrow * N + c] = acc[mf][nf][reg] + bias;
        }
      }
    }
  }
}

// ---------------- attention: 256 q-rows/block, 8 waves x 32 rows (R9 structure, proven) ----
// dbuf + issue-early STAGE + counted vmcnt(4), T2 swizzle, in-register P relayout via
// permlane, ones-MFMA rowsum, exp2 with Q pre-scaled by 0.125*log2(e), XCD swizzle.
__global__ __launch_bounds__(512, 4) void attn_kernel(
    const unsigned short* __restrict__ Q,   // (bh, s, 64), pre-scaled
    const unsigned short* __restrict__ Kg,  // (bh, t, 64)
    const unsigned short* __restrict__ VTg, // (bh, 64, t)
    unsigned short* __restrict__ Oa)        // (b, s, 1024) bf16
{
  __shared__ unsigned short S[32768];    // [buf][K 8192 us | V 8192 us] x2 = 64 KB
  const int tid = threadIdx.x;
  const int wave = tid >> 6, lane = tid & 63;
  const int l15 = lane & 15, l4 = lane >> 4;
  const int swz = (l15 & 7) << 3;        // read-side XOR, ushort units (16B granules)
  // bijective XCD swizzle (nwg=512): XCD gets 64 contiguous wg = 8 bh x 8 qb
  const int orig = blockIdx.x;
  const int wg = ((orig & 7) << 6) + (orig >> 3);
  const int qb = wg & 7, bh = wg >> 3;
  const size_t bhbase = (size_t)bh * 131072;
  const int q0 = qb * 256 + wave * 32;

  const u16x8 onesu = {0x3F80, 0x3F80, 0x3F80, 0x3F80, 0x3F80, 0x3F80, 0x3F80, 0x3F80};
  const bf16x8 ones = __builtin_bit_cast(bf16x8, onesu);

  bf16x8 qf[2][2];
#pragma unroll
  for (int m = 0; m < 2; m++)
#pragma unroll
    for (int ks = 0; ks < 2; ks++)
      qf[m][ks] = ldfrag(&Q[bhbase + (size_t)(q0 + m * 16 + l15) * 64 + ks * 32 + l4 * 8]);

  f32x4 accO[2][4];
#pragma unroll
  for (int m = 0; m < 2; m++)
#pragma unroll
    for (int n = 0; n < 4; n++) accO[m][n] = {0.f, 0.f, 0.f, 0.f};
  f32x4 accR[2] = {{0.f, 0.f, 0.f, 0.f}, {0.f, 0.f, 0.f, 0.f}};

  // stage tile jj into buffer b: 4 llds16/thread (2 K rounds + 2 V rounds), 512 threads
  auto STAGE = [&](int b, int jj) {
#pragma unroll
    for (int r = 0; r < 2; r++) {
      int D = r * 8192 + tid * 16;     // byte offset within 16KB tile
      int rowK = D >> 7;
      int colKus = ((D & 127) >> 1) ^ ((rowK & 7) << 3);
      llds16(&Kg[bhbase + (size_t)(jj * 128 + rowK) * 64 + colKus],
             &S[b * 16384 + r * 4096 + wave * 512]);
      int rowV = D >> 8;
      int colVus = ((D & 255) >> 1) ^ ((rowV & 7) << 3);
      llds16(&VTg[bhbase + (size_t)rowV * 2048 + jj * 128 + colVus],
             &S[b * 16384 + 8192 + r * 4096 + wave * 512]);
    }
  };

  int cur = 0;
  STAGE(0, 0);
  for (int j = 0; j < 16; j++) {
    if (j < 15) {
      STAGE(cur ^ 1, j + 1);
      asm volatile("s_waitcnt vmcnt(4)" ::: "memory");   // cur's 4 loads landed; j+1's in flight
    } else {
      asm volatile("s_waitcnt vmcnt(0)" ::: "memory");
    }
    __builtin_amdgcn_s_barrier();                        // all waves: cur data ready
    __builtin_amdgcn_sched_barrier(0);

    const unsigned short* Kb = &S[cur * 16384];
    const unsigned short* Vb = &S[cur * 16384 + 8192];

#pragma unroll
    for (int kt = 0; kt < 4; kt++) {
      // QK^T for the two 16-t fragments of this 32-t block
      bf16x8 kf00 = ldfrag(&Kb[((2 * kt) * 16 + l15) * 64 + ((0 * 32 + l4 * 8) ^ swz)]);
      bf16x8 kf01 = ldfrag(&Kb[((2 * kt) * 16 + l15) * 64 + ((1 * 32 + l4 * 8) ^ swz)]);
      bf16x8 kf10 = ldfrag(&Kb[((2 * kt + 1) * 16 + l15) * 64 + ((0 * 32 + l4 * 8) ^ swz)]);
      bf16x8 kf11 = ldfrag(&Kb[((2 * kt + 1) * 16 + l15) * 64 + ((1 * 32 + l4 * 8) ^ swz)]);
      f32x4 sa = {0.f, 0.f, 0.f, 0.f}, sb = sa, sc = sa, sd = sa;
      __builtin_amdgcn_s_setprio(1);
      sa = mfma16(kf00, qf[0][0], sa); sb = mfma16(kf00, qf[1][0], sb);
      sc = mfma16(kf10, qf[0][0], sc); sd = mfma16(kf10, qf[1][0], sd);
      sa = mfma16(kf01, qf[0][1], sa); sb = mfma16(kf01, qf[1][1], sb);
      sc = mfma16(kf11, qf[0][1], sc); sd = mfma16(kf11, qf[1][1], sd);
      __builtin_amdgcn_s_setprio(0);

      // V fragments (independent of QK chain -> overlaps MFMA latency)
      bf16x8 vf[4];
#pragma unroll
      for (int n = 0; n < 4; n++)
        vf[n] = ldfrag(&Vb[(n * 16 + l15) * 128 + ((kt * 32 + l4 * 8) ^ swz)]);

      // exp2 + pack + 4x4 u32 transpose over l4 groups:
      //   dest lane(g1,g0) word(w1,w0) <- lane(g0,w1) word(g1,w0)
      bf16x8 pf[2];
#pragma unroll
      for (int m = 0; m < 2; m++) {
        const f32x4 se = (m == 0) ? sa : sb;   // tf = 2kt
        const f32x4 so = (m == 0) ? sc : sd;   // tf = 2kt+1
        uint32_t V0, V1, V2, V3;
        {
          u16x4 pk;
#pragma unroll
          for (int r = 0; r < 4; r++) pk[r] = f2bf(__builtin_amdgcn_exp2f(se[r]));
          u32x2 w = __builtin_bit_cast(u32x2, pk);
          V0 = w[0]; V1 = w[1];
        }
        {
          u16x4 pk;
#pragma unroll
          for (int r = 0; r < 4; r++) pk[r] = f2bf(__builtin_amdgcn_exp2f(so[r]));
          u32x2 w = __builtin_bit_cast(u32x2, pk);
          V2 = w[0]; V3 = w[1];
        }
        asm("s_nop 1\n\t"
            "v_permlane32_swap_b32 %0, %2\n\t"
            "v_permlane32_swap_b32 %1, %3\n\t"
            "v_permlane16_swap_b32 %0, %2\n\t"
            "v_permlane16_swap_b32 %1, %3"
            : "+v"(V0), "+v"(V1), "+v"(V2), "+v"(V3));
        u32x4 fw = {V0, V1, V2, V3};
        pf[m] = __builtin_bit_cast(bf16x8, fw);
      }

      __builtin_amdgcn_s_setprio(1);
#pragma unroll
      for (int m = 0; m < 2; m++) {
        accR[m] = mfma16(pf[m], ones, accR[m]);   // rowsum on the matrix pipe
#pragma unroll
        for (int n = 0; n < 4; n++)
          accO[m][n] = mfma16(pf[m], vf[n], accO[m][n]);
      }
      __builtin_amdgcn_s_setprio(0);
    }

    __builtin_amdgcn_s_barrier();        // all waves done reading cur -> safe to overwrite
    cur ^= 1;
  }

  const int b = bh >> 4, h = bh & 15;
#pragma unroll
  for (int m = 0; m < 2; m++)
#pragma unroll
    for (int reg = 0; reg < 4; reg++) {
      float inv = 1.0f / accR[m][reg];   // rowsum for srow (C layout: row = l4*4+reg)
      int srow = q0 + m * 16 + l4 * 4 + reg;
#pragma unroll
      for (int n = 0; n < 4; n++) {
        float v = accO[m][n][reg] * inv;
        Oa[((size_t)(b * 2048) + srow) * 1024 + h * 64 + n * 16 + l15] = f2bf(v);
      }
    }
}

extern "C" void kernel_launch(void* const* d_in, const int* in_sizes, int n_in,
                              void* d_out, int out_size, void* d_ws, size_t ws_size,
                              hipStream_t stream) {
  (void)in_sizes; (void)n_in; (void)out_size; (void)ws_size;
  const float* x   = (const float*)d_in[0];
  const float* lng = (const float*)d_in[1];
  const float* lnb = (const float*)d_in[2];
  const float* wq  = (const float*)d_in[3];
  const float* bq  = (const float*)d_in[4];
  const float* wk  = (const float*)d_in[5];
  const float* bk  = (const float*)d_in[6];
  const float* wv  = (const float*)d_in[7];
  const float* bv  = (const float*)d_in[8];
  const float* wo  = (const float*)d_in[9];
  const float* bo  = (const float*)d_in[10];

  unsigned short* ws = (unsigned short*)d_ws;
  const size_t NE = 8388608;                    // 8192*1024
  unsigned short* xn  = ws;                     // bf16 LN(x)
  unsigned short* xb  = ws + NE;                // bf16 raw x
  unsigned short* wT  = ws + 2 * NE;            // (3072,1024) W^T bf16
  unsigned short* woT = wT + 3145728;           // (1024,1024) wo^T bf16
  unsigned short* qkv = woT + 1048576;          // q|k (bh,t,64) | vT (bh,64,t) bf16
  unsigned short* oat = xb;                     // alias: xb dead after GEMM1

  prep_kernel<<<dim3(9216), 256, 0, stream>>>(x, lng, lnb, xn, xb, wq, wk, wv, wo, wT, woT);
  gemm_kernel<0><<<dim3(1536), 256, 0, stream>>>(xn, xb, wT, bq, bk, bv, qkv, 8192, 3072, 1024);
  attn_kernel<<<dim3(512), 512, 0, stream>>>(qkv, qkv + NE, qkv + 2 * NE, oat);
  gemm_kernel<1><<<dim3(512), 256, 0, stream>>>(oat, oat, woT, bo, bo, bo, d_out, 8192, 1024, 1024);
}